// Round 1
// baseline (1904.001 us; speedup 1.0000x reference)
//
#include <hip/hip_runtime.h>
#include <hip/hip_bf16.h>
#include <cstdint>

#define N_NODES 100000
#define N_EDGES 3200000

// ------------------------------------------------------------------
// Weight packing: Wcat[512][192] = [W1 (128) | Ww (40) | Wa (2) | pad]
// ------------------------------------------------------------------
__global__ void pack_weights(const float* __restrict__ W1, const float* __restrict__ b1,
                             const float* __restrict__ Ww, const float* __restrict__ bw,
                             const float* __restrict__ Wa, const float* __restrict__ ba,
                             float* __restrict__ Wcat, float* __restrict__ bcat) {
    int k = blockIdx.x;      // 0..511
    int c = threadIdx.x;     // 0..191
    float v;
    if (c < 128)      v = W1[k * 128 + c];
    else if (c < 168) v = Ww[k * 40 + (c - 128)];
    else if (c < 170) v = Wa[k * 2 + (c - 168)];
    else              v = 0.f;
    Wcat[k * 192 + c] = v;
    if (k == 0) {
        float b;
        if (c < 128)      b = b1[c];
        else if (c < 168) b = bw[c - 128];
        else if (c < 170) b = ba[c - 168];
        else              b = 0.f;
        bcat[c] = b;
    }
}

// ------------------------------------------------------------------
// Degree + CSR build
// ------------------------------------------------------------------
__global__ void init_deg_cnt(float* deg, int* cnt, int n) {
    int i = blockIdx.x * 256 + threadIdx.x;
    if (i < n) { deg[i] = 1.0f; cnt[i] = 0; }   // self-loop weight 1
}

__global__ void deg_count(const int* __restrict__ ei, const float* __restrict__ ew,
                          float* deg, int* cnt, int e) {
    int i = blockIdx.x * 256 + threadIdx.x;
    if (i < e) {
        int c = ei[e + i];               // col = edge_index[1]
        atomicAdd(&deg[c], ew[i]);
        atomicAdd(&cnt[c], 1);
    }
}

__global__ void finalize_dinv(float* deg_dinv, int n) {
    int i = blockIdx.x * 256 + threadIdx.x;
    if (i < n) deg_dinv[i] = rsqrtf(deg_dinv[i]);   // deg >= 1 always
}

__global__ void scan_blocks(const int* __restrict__ cnt, int* __restrict__ ptr,
                            int* __restrict__ bsum, int n) {
    __shared__ int s[1024];
    int tid = threadIdx.x;
    int i = blockIdx.x * 1024 + tid;
    int v = (i < n) ? cnt[i] : 0;
    s[tid] = v;
    __syncthreads();
    for (int off = 1; off < 1024; off <<= 1) {
        int t = (tid >= off) ? s[tid - off] : 0;
        __syncthreads();
        s[tid] += t;
        __syncthreads();
    }
    if (i < n) ptr[i] = s[tid] - v;              // exclusive
    if (tid == 1023) bsum[blockIdx.x] = s[1023]; // block total
}

__global__ void scan_bsums(int* bsum, int nb) {
    __shared__ int s[1024];
    int tid = threadIdx.x;
    int v = (tid < nb) ? bsum[tid] : 0;
    s[tid] = v;
    __syncthreads();
    for (int off = 1; off < 1024; off <<= 1) {
        int t = (tid >= off) ? s[tid - off] : 0;
        __syncthreads();
        s[tid] += t;
        __syncthreads();
    }
    if (tid < nb) bsum[tid] = s[tid] - v;        // exclusive
}

__global__ void scan_add(int* __restrict__ ptr, const int* __restrict__ bsum,
                         int* __restrict__ cnt, int n, int total) {
    int i = blockIdx.x * 1024 + threadIdx.x;
    if (i < n) { ptr[i] += bsum[blockIdx.x]; cnt[i] = 0; }  // cnt reset -> fill cursor
    if (i == 0) ptr[n] = total;
}

__global__ void fill_csr(const int* __restrict__ ei, const float* __restrict__ ew,
                         const float* __restrict__ dinv, const int* __restrict__ ptr,
                         int* cnt, int* __restrict__ srcS, float* __restrict__ wnS, int e) {
    int i = blockIdx.x * 256 + threadIdx.x;
    if (i < e) {
        int r = ei[i];           // source
        int d = ei[e + i];       // dest
        int p = ptr[d] + atomicAdd(&cnt[d], 1);
        srcS[p] = r;
        wnS[p] = ew[i] * dinv[r] * dinv[d];   // fold symmetric norm into edge weight
    }
}

// ------------------------------------------------------------------
// fp32 tiled GEMM: 64x64 tile, BK=16, 256 threads, 4x4 per thread.
// EPI 0: plain store C0[m*ldb+n]   (used for h @ Wc, ldb==ncols==128)
// EPI 1: piecewise epilogue: c<128 -> relu->C0[N,128]; c<168 -> C1[N,40];
//        c<170 -> C2[N,2]; bias added from bcat.
// ------------------------------------------------------------------
template <int EPI>
__global__ __launch_bounds__(256) void gemm_tile(
    const float* __restrict__ A, const float* __restrict__ B,
    int M, int K, int ldb,
    float* __restrict__ C0, float* __restrict__ C1, float* __restrict__ C2,
    const float* __restrict__ bias) {
    __shared__ __align__(16) float Ast[16][68];  // transposed A tile [k][m], padded
    __shared__ __align__(16) float Bs[16][68];   // B tile [k][n], padded

    int tid = threadIdx.x;
    int m0 = blockIdx.y * 64;
    int n0 = blockIdx.x * 64;
    int tx = tid & 15, ty = tid >> 4;

    int la_m = tid >> 2;            // 0..63
    int la_k = (tid & 3) << 2;      // 0,4,8,12
    int lb_k = tid >> 4;            // 0..15
    int lb_n = (tid & 15) << 2;     // 0..60

    float acc[4][4] = {};

    for (int kc = 0; kc < K; kc += 16) {
        float4 av;
        if (m0 + la_m < M) av = *(const float4*)&A[(size_t)(m0 + la_m) * K + kc + la_k];
        else av = make_float4(0.f, 0.f, 0.f, 0.f);
        float4 bv = *(const float4*)&B[(size_t)(kc + lb_k) * ldb + n0 + lb_n];

        Ast[la_k + 0][la_m] = av.x;
        Ast[la_k + 1][la_m] = av.y;
        Ast[la_k + 2][la_m] = av.z;
        Ast[la_k + 3][la_m] = av.w;
        *(float4*)&Bs[lb_k][lb_n] = bv;
        __syncthreads();

#pragma unroll
        for (int k = 0; k < 16; ++k) {
            float4 a4 = *(const float4*)&Ast[k][ty << 2];
            float4 b4 = *(const float4*)&Bs[k][tx << 2];
            float ar[4] = {a4.x, a4.y, a4.z, a4.w};
            float br[4] = {b4.x, b4.y, b4.z, b4.w};
#pragma unroll
            for (int i = 0; i < 4; ++i)
#pragma unroll
                for (int j = 0; j < 4; ++j) acc[i][j] += ar[i] * br[j];
        }
        __syncthreads();
    }

#pragma unroll
    for (int i = 0; i < 4; ++i) {
        int m = m0 + (ty << 2) + i;
        if (m >= M) continue;
#pragma unroll
        for (int j = 0; j < 4; ++j) {
            int n = n0 + (tx << 2) + j;
            float v = acc[i][j];
            if (EPI == 0) {
                C0[(size_t)m * ldb + n] = v;
            } else {
                v += bias[n];
                if (n < 128)      C0[(size_t)m * 128 + n] = fmaxf(v, 0.f);
                else if (n < 168) C1[(size_t)m * 40 + (n - 128)] = v;
                else if (n < 170) C2[(size_t)m * 2 + (n - 168)] = v;
            }
        }
    }
}

// ------------------------------------------------------------------
// GCN propagation via destination-CSR: one block per dst node,
// 128 threads = 128 features. out = relu(scatter + selfloop + bias)
// ------------------------------------------------------------------
__global__ void propagate(const float* __restrict__ tmp, float* __restrict__ outH,
                          const float* __restrict__ bias, const float* __restrict__ dinv,
                          const int* __restrict__ ptr, const int* __restrict__ srcS,
                          const float* __restrict__ wnS) {
    int d = blockIdx.x;
    int f = threadIdx.x;
    float di = dinv[d];
    float acc = di * di * tmp[(size_t)d * 128 + f];   // self loop (weight 1)
    int p0 = ptr[d], p1 = ptr[d + 1];
    for (int p = p0; p < p1; ++p) {
        int s = srcS[p];
        float w = wnS[p];
        acc += w * tmp[(size_t)s * 128 + f];
    }
    float v = acc + bias[f];
    outH[(size_t)d * 128 + f] = v > 0.f ? v : 0.f;
}

// ------------------------------------------------------------------
// Final: out = (h2 @ W2 + b2) * a0 + wide * a1, attn = softmax(logits)
// 8 nodes/block, 320 threads (node = tid/40, col = tid%40)
// ------------------------------------------------------------------
__global__ void final_k(const float* __restrict__ h2, const float* __restrict__ wide,
                        const float* __restrict__ attnL, const float* __restrict__ W2,
                        const float* __restrict__ b2, float* __restrict__ out) {
    __shared__ __align__(16) float hs[8][132];
    __shared__ __align__(16) float w2t[40][132];
    int tid = threadIdx.x;
    int m0 = blockIdx.x * 8;

    for (int idx = tid; idx < 8 * 128; idx += 320) {
        hs[idx >> 7][idx & 127] = h2[(size_t)m0 * 128 + idx];
    }
    for (int idx = tid; idx < 40 * 128; idx += 320) {
        int c = idx >> 7, k = idx & 127;
        w2t[c][k] = W2[k * 40 + c];
    }
    __syncthreads();

    int c = tid % 40;
    int nl = tid / 40;   // 0..7
    float acc = 0.f;
#pragma unroll
    for (int k = 0; k < 128; k += 4) {
        float4 h4 = *(const float4*)&hs[nl][k];
        float4 w4 = *(const float4*)&w2t[c][k];
        acc += h4.x * w4.x + h4.y * w4.y + h4.z * w4.z + h4.w * w4.w;
    }
    int m = m0 + nl;
    float l0 = attnL[m * 2], l1 = attnL[m * 2 + 1];
    float mx = fmaxf(l0, l1);
    float e0 = __expf(l0 - mx), e1 = __expf(l1 - mx);
    float inv = 1.f / (e0 + e1);
    out[(size_t)m * 40 + c] = (acc + b2[c]) * (e0 * inv) + wide[(size_t)m * 40 + c] * (e1 * inv);
}

// ------------------------------------------------------------------
extern "C" void kernel_launch(void* const* d_in, const int* in_sizes, int n_in,
                              void* d_out, int out_size, void* d_ws, size_t ws_size,
                              hipStream_t stream) {
    (void)in_sizes; (void)n_in; (void)out_size; (void)ws_size;
    const float* x   = (const float*)d_in[0];
    const int*   ei  = (const int*)d_in[1];
    const float* ew  = (const float*)d_in[2];
    const float* W1  = (const float*)d_in[3];
    const float* b1  = (const float*)d_in[4];
    const float* Wc1 = (const float*)d_in[5];
    const float* bc1 = (const float*)d_in[6];
    const float* Wc2 = (const float*)d_in[7];
    const float* bc2 = (const float*)d_in[8];
    const float* W2  = (const float*)d_in[9];
    const float* b2  = (const float*)d_in[10];
    const float* Ww  = (const float*)d_in[11];
    const float* bw  = (const float*)d_in[12];
    const float* Wa  = (const float*)d_in[13];
    const float* ba  = (const float*)d_in[14];
    float* out = (float*)d_out;

    const int N = N_NODES, E = N_EDGES;
    char* ws = (char*)d_ws;
    size_t off = 0;
    auto alloc = [&](size_t bytes) -> void* {
        void* p = ws + off;
        off = (off + bytes + 255) & ~(size_t)255;
        return p;
    };
    float* bufA  = (float*)alloc((size_t)N * 128 * 4);  // h buffers (ping)
    float* bufB  = (float*)alloc((size_t)N * 128 * 4);  // (pong)
    float* wide  = (float*)alloc((size_t)N * 40 * 4);
    float* attnL = (float*)alloc((size_t)N * 2 * 4);
    float* dinv  = (float*)alloc((size_t)N * 4);        // deg then dinv in place
    int*   ptr   = (int*)alloc((size_t)(N + 1) * 4);
    int*   cnt   = (int*)alloc((size_t)N * 4);
    int*   bsum  = (int*)alloc(1024 * 4);
    int*   srcS  = (int*)alloc((size_t)E * 4);
    float* wnS   = (float*)alloc((size_t)E * 4);
    float* Wcat  = (float*)alloc((size_t)512 * 192 * 4);
    float* bcat  = (float*)alloc(192 * 4);

    // --- graph preprocessing (per call; same work every call) ---
    pack_weights<<<512, 192, 0, stream>>>(W1, b1, Ww, bw, Wa, ba, Wcat, bcat);
    init_deg_cnt<<<(N + 255) / 256, 256, 0, stream>>>(dinv, cnt, N);
    deg_count<<<(E + 255) / 256, 256, 0, stream>>>(ei, ew, dinv, cnt, E);
    finalize_dinv<<<(N + 255) / 256, 256, 0, stream>>>(dinv, N);
    int nb = (N + 1023) / 1024;
    scan_blocks<<<nb, 1024, 0, stream>>>(cnt, ptr, bsum, N);
    scan_bsums<<<1, 1024, 0, stream>>>(bsum, nb);
    scan_add<<<nb, 1024, 0, stream>>>(ptr, bsum, cnt, N, E);
    fill_csr<<<(E + 255) / 256, 256, 0, stream>>>(ei, ew, dinv, ptr, cnt, srcS, wnS, E);

    // --- fused input GEMM: h0 = relu(x@W1+b1), wide = x@Ww+bw, attnL = x@Wa+ba ---
    dim3 g1(3, (N + 63) / 64);
    gemm_tile<1><<<g1, 256, 0, stream>>>(x, Wcat, N, 512, 192, bufA, wide, attnL, bcat);

    // --- conv layer 1 ---
    dim3 g2(2, (N + 63) / 64);
    gemm_tile<0><<<g2, 256, 0, stream>>>(bufA, Wc1, N, 128, 128, bufB, nullptr, nullptr, nullptr);
    propagate<<<N, 128, 0, stream>>>(bufB, bufA, bc1, dinv, ptr, srcS, wnS);

    // --- conv layer 2 ---
    gemm_tile<0><<<g2, 256, 0, stream>>>(bufA, Wc2, N, 128, 128, bufB, nullptr, nullptr, nullptr);
    propagate<<<N, 128, 0, stream>>>(bufB, bufA, bc2, dinv, ptr, srcS, wnS);

    // --- final fusion ---
    final_k<<<N / 8, 320, 0, stream>>>(bufA, wide, attnL, W2, b2, out);
}

// Round 2
// 1258.486 us; speedup vs baseline: 1.5129x; 1.5129x over previous
//
#include <hip/hip_runtime.h>
#include <hip/hip_bf16.h>
#include <cstdint>

#define N_NODES 100000
#define N_EDGES 3200000

typedef __attribute__((ext_vector_type(8))) short short8;
typedef __attribute__((ext_vector_type(4))) float floatx4;

__device__ __forceinline__ unsigned short f2bf(float f) {
    unsigned u = __float_as_uint(f);
    u += 0x7fff + ((u >> 16) & 1);          // round-to-nearest-even
    return (unsigned short)(u >> 16);
}
__device__ __forceinline__ float bf2f(unsigned short s) {
    return __uint_as_float(((unsigned)s) << 16);
}
__device__ __forceinline__ float bflo(unsigned u) {   // low bf16 of packed pair
    return __uint_as_float(u << 16);
}
__device__ __forceinline__ float bfhi(unsigned u) {   // high bf16 of packed pair
    return __uint_as_float(u & 0xffff0000u);
}

// ------------------------------------------------------------------
// Weight packing (transposed, bf16): WcatT[192][512] = [W1|Ww|Wa|pad]^T
// ------------------------------------------------------------------
__global__ void pack_wcatT(const float* __restrict__ W1, const float* __restrict__ b1,
                           const float* __restrict__ Ww, const float* __restrict__ bw,
                           const float* __restrict__ Wa, const float* __restrict__ ba,
                           unsigned short* __restrict__ WcatT, float* __restrict__ bcat) {
    int c = blockIdx.x;          // 0..191 (output column)
    for (int kk = threadIdx.x; kk < 512; kk += 256) {
        float v;
        if (c < 128)      v = W1[kk * 128 + c];
        else if (c < 168) v = Ww[kk * 40 + (c - 128)];
        else if (c < 170) v = Wa[kk * 2 + (c - 168)];
        else              v = 0.f;
        WcatT[(size_t)c * 512 + kk] = f2bf(v);
    }
    if (threadIdx.x == 0) {
        float b;
        if (c < 128)      b = b1[c];
        else if (c < 168) b = bw[c - 128];
        else if (c < 170) b = ba[c - 168];
        else              b = 0.f;
        bcat[c] = b;
    }
}

__global__ void pack_wcT(const float* __restrict__ Wc1, const float* __restrict__ Wc2,
                         unsigned short* __restrict__ T1, unsigned short* __restrict__ T2) {
    int c = blockIdx.x & 127;
    const float* W = (blockIdx.x < 128) ? Wc1 : Wc2;
    unsigned short* O = (blockIdx.x < 128) ? T1 : T2;
    int k = threadIdx.x;                  // 0..127
    O[(size_t)c * 128 + k] = f2bf(W[k * 128 + c]);
}

// ------------------------------------------------------------------
// Degree + CSR build
// ------------------------------------------------------------------
__global__ void init_deg_cnt(float* deg, int* cnt, int n) {
    int i = blockIdx.x * 256 + threadIdx.x;
    if (i < n) { deg[i] = 1.0f; cnt[i] = 0; }   // self-loop weight 1
}

__global__ void deg_count(const int* __restrict__ ei, const float* __restrict__ ew,
                          float* deg, int* cnt, int e) {
    int i = blockIdx.x * 256 + threadIdx.x;
    if (i < e) {
        int c = ei[e + i];               // col = edge_index[1]
        atomicAdd(&deg[c], ew[i]);
        atomicAdd(&cnt[c], 1);
    }
}

__global__ void finalize_dinv(float* deg_dinv, int n) {
    int i = blockIdx.x * 256 + threadIdx.x;
    if (i < n) deg_dinv[i] = rsqrtf(deg_dinv[i]);   // deg >= 1 always
}

__global__ void scan_blocks(const int* __restrict__ cnt, int* __restrict__ ptr,
                            int* __restrict__ bsum, int n) {
    __shared__ int s[1024];
    int tid = threadIdx.x;
    int i = blockIdx.x * 1024 + tid;
    int v = (i < n) ? cnt[i] : 0;
    s[tid] = v;
    __syncthreads();
    for (int off = 1; off < 1024; off <<= 1) {
        int t = (tid >= off) ? s[tid - off] : 0;
        __syncthreads();
        s[tid] += t;
        __syncthreads();
    }
    if (i < n) ptr[i] = s[tid] - v;              // exclusive
    if (tid == 1023) bsum[blockIdx.x] = s[1023]; // block total
}

__global__ void scan_bsums(int* bsum, int nb) {
    __shared__ int s[1024];
    int tid = threadIdx.x;
    int v = (tid < nb) ? bsum[tid] : 0;
    s[tid] = v;
    __syncthreads();
    for (int off = 1; off < 1024; off <<= 1) {
        int t = (tid >= off) ? s[tid - off] : 0;
        __syncthreads();
        s[tid] += t;
        __syncthreads();
    }
    if (tid < nb) bsum[tid] = s[tid] - v;        // exclusive
}

__global__ void scan_add(int* __restrict__ ptr, const int* __restrict__ bsum,
                         int* __restrict__ cnt, int n, int total) {
    int i = blockIdx.x * 1024 + threadIdx.x;
    if (i < n) { ptr[i] += bsum[blockIdx.x]; cnt[i] = 0; }  // cnt reset -> fill cursor
    if (i == 0) ptr[n] = total;
}

__global__ void fill_csr(const int* __restrict__ ei, const float* __restrict__ ew,
                         const float* __restrict__ dinv, const int* __restrict__ ptr,
                         int* cnt, int* __restrict__ srcS, float* __restrict__ wnS, int e) {
    int i = blockIdx.x * 256 + threadIdx.x;
    if (i < e) {
        int r = ei[i];           // source
        int d = ei[e + i];       // dest
        int p = ptr[d] + atomicAdd(&cnt[d], 1);
        srcS[p] = r;
        wnS[p] = ew[i] * dinv[r] * dinv[d];   // fold symmetric norm into edge weight
    }
}

// ------------------------------------------------------------------
// MFMA bf16 GEMM: block = 256 thr (4 waves), tile 64(M) x (32*NT)(N),
// K-step 32, wave = 32x(16*NT): 2x NT mfma_f32_16x16x32_bf16.
// A is [M][K]: fp32 (AF32=1, converted during staging) or bf16 bits.
// BT is [Ntot][K] bf16 bits (pre-transposed weights).
// EPI 0: C0 bf16 [M][128]  (conv tmp, pre-propagation)
// EPI 1: n<128 -> relu+bias -> C0 bf16 [M][128]; n<168 -> C1 fp32 [M][40];
//        n<170 -> C2 fp32 [M][2]   (bias from bcat)
// ------------------------------------------------------------------
template <int EPI, int NT, int AF32>
__global__ __launch_bounds__(256) void gemm_mfma(
    const void* __restrict__ Avoid, const unsigned short* __restrict__ BT,
    int M, int K,
    unsigned short* __restrict__ C0, float* __restrict__ C1, float* __restrict__ C2,
    const float* __restrict__ bias) {
    constexpr int NB = 32 * NT;                  // full N width
    __shared__ __align__(16) unsigned short Ast[64 * 40];
    __shared__ __align__(16) unsigned short Bst[NB * 40];

    int tid = threadIdx.x;
    int m0 = blockIdx.x * 64;
    int wave = tid >> 6, lane = tid & 63;
    int quad = lane >> 4, mi = lane & 15;
    int wm = (wave >> 1) * 32;                   // wave M offset (0 or 32)
    int wn = (wave & 1) * (16 * NT);             // wave N offset

    int srow = tid >> 2;                         // 0..63
    int sk8 = (tid & 3) * 8;                     // 0,8,16,24

    int arow = m0 + srow; if (arow >= M) arow = M - 1;

    floatx4 acc[2][NT] = {};

    for (int kc = 0; kc < K; kc += 32) {
        // ---- stage A (64 x 32) ----
        if (AF32) {
            const float* Af = (const float*)Avoid;
            const float4* ap = (const float4*)(Af + (size_t)arow * K + kc + sk8);
            float4 f0 = ap[0], f1 = ap[1];
            union { unsigned short us[8]; uint4 v; } pk;
            pk.us[0] = f2bf(f0.x); pk.us[1] = f2bf(f0.y);
            pk.us[2] = f2bf(f0.z); pk.us[3] = f2bf(f0.w);
            pk.us[4] = f2bf(f1.x); pk.us[5] = f2bf(f1.y);
            pk.us[6] = f2bf(f1.z); pk.us[7] = f2bf(f1.w);
            *(uint4*)&Ast[srow * 40 + sk8] = pk.v;
        } else {
            const unsigned short* Ab = (const unsigned short*)Avoid;
            uint4 av = *(const uint4*)(Ab + (size_t)arow * K + kc + sk8);
            *(uint4*)&Ast[srow * 40 + sk8] = av;
        }
        // ---- stage B (NB x 32) ----
#pragma unroll
        for (int i = tid; i < NB * 4; i += 256) {
            int brow = i >> 2;
            int bk8 = (i & 3) * 8;
            uint4 bv = *(const uint4*)(BT + (size_t)brow * K + kc + bk8);
            *(uint4*)&Bst[brow * 40 + bk8] = bv;
        }
        __syncthreads();

        short8 a0 = *(const short8*)&Ast[(wm + mi) * 40 + quad * 8];
        short8 a1 = *(const short8*)&Ast[(wm + 16 + mi) * 40 + quad * 8];
#pragma unroll
        for (int nt = 0; nt < NT; ++nt) {
            short8 b = *(const short8*)&Bst[(wn + nt * 16 + mi) * 40 + quad * 8];
            acc[0][nt] = __builtin_amdgcn_mfma_f32_16x16x32_bf16(a0, b, acc[0][nt], 0, 0, 0);
            acc[1][nt] = __builtin_amdgcn_mfma_f32_16x16x32_bf16(a1, b, acc[1][nt], 0, 0, 0);
        }
        __syncthreads();
    }

    // ---- epilogue: D layout col=lane&15, row=quad*4+r ----
#pragma unroll
    for (int mt = 0; mt < 2; ++mt) {
#pragma unroll
        for (int nt = 0; nt < NT; ++nt) {
            floatx4 v = acc[mt][nt];
            int gn = wn + nt * 16 + mi;
#pragma unroll
            for (int r = 0; r < 4; ++r) {
                int gm = m0 + wm + mt * 16 + quad * 4 + r;
                if (gm >= M) continue;
                float val = v[r];
                if (EPI == 0) {
                    C0[(size_t)gm * 128 + gn] = f2bf(val);
                } else {
                    val += bias[gn];
                    if (gn < 128)      C0[(size_t)gm * 128 + gn] = f2bf(fmaxf(val, 0.f));
                    else if (gn < 168) C1[(size_t)gm * 40 + (gn - 128)] = val;
                    else if (gn < 170) C2[(size_t)gm * 2 + (gn - 168)] = val;
                }
            }
        }
    }
}

// ------------------------------------------------------------------
// GCN propagation, dst-CSR, bf16 messages. One WAVE per dst node:
// 64 lanes x bf16x2 = full 128-feature row per gather instruction.
// out = relu(scatter + selfloop + bias) -> bf16
// ------------------------------------------------------------------
__global__ __launch_bounds__(256) void propagate(
    const unsigned int* __restrict__ tmp2,    // [M][64] packed bf16x2
    unsigned int* __restrict__ out2,          // [M][64] packed bf16x2
    const float* __restrict__ bias, const float* __restrict__ dinv,
    const int* __restrict__ ptr, const int* __restrict__ srcS,
    const float* __restrict__ wnS, int n) {
    int wave = threadIdx.x >> 6, lane = threadIdx.x & 63;
    int d = blockIdx.x * 4 + wave;
    if (d >= n) return;

    float di = dinv[d];
    float wsl = di * di;                     // self-loop weight
    unsigned u = tmp2[(size_t)d * 64 + lane];
    float acc0 = wsl * bflo(u);
    float acc1 = wsl * bfhi(u);

    int p = ptr[d], p1 = ptr[d + 1];
    for (; p + 4 <= p1; p += 4) {
        int s0 = srcS[p], s1 = srcS[p + 1], s2 = srcS[p + 2], s3 = srcS[p + 3];
        float w0 = wnS[p], w1 = wnS[p + 1], w2 = wnS[p + 2], w3 = wnS[p + 3];
        unsigned a = tmp2[(size_t)s0 * 64 + lane];
        unsigned b = tmp2[(size_t)s1 * 64 + lane];
        unsigned c = tmp2[(size_t)s2 * 64 + lane];
        unsigned e = tmp2[(size_t)s3 * 64 + lane];
        acc0 += w0 * bflo(a); acc1 += w0 * bfhi(a);
        acc0 += w1 * bflo(b); acc1 += w1 * bfhi(b);
        acc0 += w2 * bflo(c); acc1 += w2 * bfhi(c);
        acc0 += w3 * bflo(e); acc1 += w3 * bfhi(e);
    }
    for (; p < p1; ++p) {
        int s = srcS[p];
        float w = wnS[p];
        unsigned a = tmp2[(size_t)s * 64 + lane];
        acc0 += w * bflo(a); acc1 += w * bfhi(a);
    }
    float v0 = fmaxf(acc0 + bias[2 * lane], 0.f);
    float v1 = fmaxf(acc1 + bias[2 * lane + 1], 0.f);
    out2[(size_t)d * 64 + lane] = (unsigned)f2bf(v0) | ((unsigned)f2bf(v1) << 16);
}

// ------------------------------------------------------------------
// Final: out = (h2 @ W2 + b2) * a0 + wide * a1, attn = softmax(logits)
// 8 nodes/block, 320 threads (node = tid/40, col = tid%40). h2 is bf16.
// ------------------------------------------------------------------
__global__ void final_k(const unsigned short* __restrict__ h2, const float* __restrict__ wide,
                        const float* __restrict__ attnL, const float* __restrict__ W2,
                        const float* __restrict__ b2, float* __restrict__ out) {
    __shared__ __align__(16) float hs[8][132];
    __shared__ __align__(16) float w2t[40][132];
    int tid = threadIdx.x;
    int m0 = blockIdx.x * 8;

    for (int idx = tid; idx < 8 * 128; idx += 320) {
        hs[idx >> 7][idx & 127] = bf2f(h2[(size_t)m0 * 128 + idx]);
    }
    for (int idx = tid; idx < 40 * 128; idx += 320) {
        int c = idx >> 7, k = idx & 127;
        w2t[c][k] = W2[k * 40 + c];
    }
    __syncthreads();

    int c = tid % 40;
    int nl = tid / 40;   // 0..7
    float acc = 0.f;
#pragma unroll
    for (int k = 0; k < 128; k += 4) {
        float4 h4 = *(const float4*)&hs[nl][k];
        float4 w4 = *(const float4*)&w2t[c][k];
        acc += h4.x * w4.x + h4.y * w4.y + h4.z * w4.z + h4.w * w4.w;
    }
    int m = m0 + nl;
    float l0 = attnL[m * 2], l1 = attnL[m * 2 + 1];
    float mx = fmaxf(l0, l1);
    float e0 = __expf(l0 - mx), e1 = __expf(l1 - mx);
    float inv = 1.f / (e0 + e1);
    out[(size_t)m * 40 + c] = (acc + b2[c]) * (e0 * inv) + wide[(size_t)m * 40 + c] * (e1 * inv);
}

// ------------------------------------------------------------------
extern "C" void kernel_launch(void* const* d_in, const int* in_sizes, int n_in,
                              void* d_out, int out_size, void* d_ws, size_t ws_size,
                              hipStream_t stream) {
    (void)in_sizes; (void)n_in; (void)out_size; (void)ws_size;
    const float* x   = (const float*)d_in[0];
    const int*   ei  = (const int*)d_in[1];
    const float* ew  = (const float*)d_in[2];
    const float* W1  = (const float*)d_in[3];
    const float* b1  = (const float*)d_in[4];
    const float* Wc1 = (const float*)d_in[5];
    const float* bc1 = (const float*)d_in[6];
    const float* Wc2 = (const float*)d_in[7];
    const float* bc2 = (const float*)d_in[8];
    const float* W2  = (const float*)d_in[9];
    const float* b2  = (const float*)d_in[10];
    const float* Ww  = (const float*)d_in[11];
    const float* bw  = (const float*)d_in[12];
    const float* Wa  = (const float*)d_in[13];
    const float* ba  = (const float*)d_in[14];
    float* out = (float*)d_out;

    const int N = N_NODES, E = N_EDGES;
    char* ws = (char*)d_ws;
    size_t off = 0;
    auto alloc = [&](size_t bytes) -> void* {
        void* p = ws + off;
        off = (off + bytes + 255) & ~(size_t)255;
        return p;
    };
    unsigned short* bufA = (unsigned short*)alloc((size_t)N * 128 * 2);  // h ping (bf16)
    unsigned short* bufB = (unsigned short*)alloc((size_t)N * 128 * 2);  // h pong (bf16)
    float* wide  = (float*)alloc((size_t)N * 40 * 4);
    float* attnL = (float*)alloc((size_t)N * 2 * 4);
    float* dinv  = (float*)alloc((size_t)N * 4);
    int*   ptr   = (int*)alloc((size_t)(N + 1) * 4);
    int*   cnt   = (int*)alloc((size_t)N * 4);
    int*   bsum  = (int*)alloc(1024 * 4);
    int*   srcS  = (int*)alloc((size_t)E * 4);
    float* wnS   = (float*)alloc((size_t)E * 4);
    unsigned short* WcatT = (unsigned short*)alloc((size_t)192 * 512 * 2);
    unsigned short* Wc1T  = (unsigned short*)alloc((size_t)128 * 128 * 2);
    unsigned short* Wc2T  = (unsigned short*)alloc((size_t)128 * 128 * 2);
    float* bcat  = (float*)alloc(192 * 4);

    // --- weight packing (bf16, transposed to [n][K]) ---
    pack_wcatT<<<192, 256, 0, stream>>>(W1, b1, Ww, bw, Wa, ba, WcatT, bcat);
    pack_wcT<<<256, 128, 0, stream>>>(Wc1, Wc2, Wc1T, Wc2T);

    // --- graph preprocessing ---
    init_deg_cnt<<<(N + 255) / 256, 256, 0, stream>>>(dinv, cnt, N);
    deg_count<<<(E + 255) / 256, 256, 0, stream>>>(ei, ew, dinv, cnt, E);
    finalize_dinv<<<(N + 255) / 256, 256, 0, stream>>>(dinv, N);
    int nb = (N + 1023) / 1024;
    scan_blocks<<<nb, 1024, 0, stream>>>(cnt, ptr, bsum, N);
    scan_bsums<<<1, 1024, 0, stream>>>(bsum, nb);
    scan_add<<<nb, 1024, 0, stream>>>(ptr, bsum, cnt, N, E);
    fill_csr<<<(E + 255) / 256, 256, 0, stream>>>(ei, ew, dinv, ptr, cnt, srcS, wnS, E);

    const int MB = (N + 63) / 64;   // 1563 m-blocks

    // --- fused input GEMM (fp32 A, bf16 MFMA): h0/wide/attnL ---
    gemm_mfma<1, 6, 1><<<MB, 256, 0, stream>>>(x, WcatT, N, 512, bufA, wide, attnL, bcat);

    // --- conv layer 1 ---
    gemm_mfma<0, 4, 0><<<MB, 256, 0, stream>>>(bufA, Wc1T, N, 128, bufB, nullptr, nullptr, nullptr);
    propagate<<<(N + 3) / 4, 256, 0, stream>>>((const unsigned int*)bufB, (unsigned int*)bufA,
                                               bc1, dinv, ptr, srcS, wnS, N);

    // --- conv layer 2 ---
    gemm_mfma<0, 4, 0><<<MB, 256, 0, stream>>>(bufA, Wc2T, N, 128, bufB, nullptr, nullptr, nullptr);
    propagate<<<(N + 3) / 4, 256, 0, stream>>>((const unsigned int*)bufB, (unsigned int*)bufA,
                                               bc2, dinv, ptr, srcS, wnS, N);

    // --- final fusion ---
    final_k<<<N / 8, 320, 0, stream>>>(bufA, wide, attnL, W2, b2, out);
}

// Round 3
// 993.684 us; speedup vs baseline: 1.9161x; 1.2665x over previous
//
#include <hip/hip_runtime.h>
#include <hip/hip_bf16.h>
#include <cstdint>

#define N_NODES 100000
#define N_EDGES 3200000

typedef __attribute__((ext_vector_type(8))) short short8;
typedef __attribute__((ext_vector_type(4))) float floatx4;

#define FXS 8388608.0f           // 2^23 fixed-point scale for degree accum
#define MASK40 0xFFFFFFFFFFull

__device__ __forceinline__ unsigned short f2bf(float f) {
    unsigned u = __float_as_uint(f);
    u += 0x7fff + ((u >> 16) & 1);          // round-to-nearest-even
    return (unsigned short)(u >> 16);
}
__device__ __forceinline__ float bf2f(unsigned short s) {
    return __uint_as_float(((unsigned)s) << 16);
}
__device__ __forceinline__ float bflo(unsigned u) {
    return __uint_as_float(u << 16);
}
__device__ __forceinline__ float bfhi(unsigned u) {
    return __uint_as_float(u & 0xffff0000u);
}

// ------------------------------------------------------------------
// Weight packing (transposed, bf16): WcatT[192][512] = [W1|Ww|Wa|pad]^T
// ------------------------------------------------------------------
__global__ void pack_wcatT(const float* __restrict__ W1, const float* __restrict__ b1,
                           const float* __restrict__ Ww, const float* __restrict__ bw,
                           const float* __restrict__ Wa, const float* __restrict__ ba,
                           unsigned short* __restrict__ WcatT, float* __restrict__ bcat) {
    int c = blockIdx.x;          // 0..191 (output column)
    for (int kk = threadIdx.x; kk < 512; kk += 256) {
        float v;
        if (c < 128)      v = W1[kk * 128 + c];
        else if (c < 168) v = Ww[kk * 40 + (c - 128)];
        else if (c < 170) v = Wa[kk * 2 + (c - 168)];
        else              v = 0.f;
        WcatT[(size_t)c * 512 + kk] = f2bf(v);
    }
    if (threadIdx.x == 0) {
        float b;
        if (c < 128)      b = b1[c];
        else if (c < 168) b = bw[c - 128];
        else if (c < 170) b = ba[c - 168];
        else              b = 0.f;
        bcat[c] = b;
    }
}

__global__ void pack_wcT(const float* __restrict__ Wc1, const float* __restrict__ Wc2,
                         unsigned short* __restrict__ T1, unsigned short* __restrict__ T2) {
    int c = blockIdx.x & 127;
    const float* W = (blockIdx.x < 128) ? Wc1 : Wc2;
    unsigned short* O = (blockIdx.x < 128) ? T1 : T2;
    int k = threadIdx.x;                  // 0..127
    O[(size_t)c * 128 + k] = f2bf(W[k * 128 + c]);
}

// ------------------------------------------------------------------
// CSR build: ONE packed 64-bit atomic per edge.
// packed[d]: bits 40+ = count, bits 0..39 = fixed-point sum of ew.
// The atomic return value gives the edge's rank within its dst.
// ------------------------------------------------------------------
__global__ void init_packed(unsigned long long* packed, int n) {
    int i = blockIdx.x * 256 + threadIdx.x;
    if (i < n) packed[i] = 0ull;
}

__global__ void deg_rank(const int* __restrict__ ei, const float* __restrict__ ew,
                         unsigned long long* packed, int* __restrict__ rank, int e) {
    int i = blockIdx.x * 256 + threadIdx.x;
    if (i < e) {
        int d = ei[e + i];               // col = edge_index[1] = destination
        unsigned fx = (unsigned)(ew[i] * FXS);
        unsigned long long old =
            atomicAdd(&packed[d], (1ull << 40) | (unsigned long long)fx);
        rank[i] = (int)(old >> 40);
    }
}

__global__ void finalize_dinv(const unsigned long long* __restrict__ packed,
                              float* __restrict__ dinv, int n) {
    int i = blockIdx.x * 256 + threadIdx.x;
    if (i < n) {
        float deg = 1.0f + (float)(packed[i] & MASK40) * (1.0f / FXS);  // + self-loop
        dinv[i] = rsqrtf(deg);
    }
}

__global__ void scan_blocks(const unsigned long long* __restrict__ packed,
                            int* __restrict__ ptr, int* __restrict__ bsum, int n) {
    __shared__ int s[1024];
    int tid = threadIdx.x;
    int i = blockIdx.x * 1024 + tid;
    int v = (i < n) ? (int)(packed[i] >> 40) : 0;
    s[tid] = v;
    __syncthreads();
    for (int off = 1; off < 1024; off <<= 1) {
        int t = (tid >= off) ? s[tid - off] : 0;
        __syncthreads();
        s[tid] += t;
        __syncthreads();
    }
    if (i < n) ptr[i] = s[tid] - v;              // exclusive
    if (tid == 1023) bsum[blockIdx.x] = s[1023]; // block total
}

__global__ void scan_bsums(int* bsum, int nb) {
    __shared__ int s[1024];
    int tid = threadIdx.x;
    int v = (tid < nb) ? bsum[tid] : 0;
    s[tid] = v;
    __syncthreads();
    for (int off = 1; off < 1024; off <<= 1) {
        int t = (tid >= off) ? s[tid - off] : 0;
        __syncthreads();
        s[tid] += t;
        __syncthreads();
    }
    if (tid < nb) bsum[tid] = s[tid] - v;        // exclusive
}

__global__ void scan_add(int* __restrict__ ptr, const int* __restrict__ bsum,
                         int n, int total) {
    int i = blockIdx.x * 1024 + threadIdx.x;
    if (i < n) ptr[i] += bsum[blockIdx.x];
    if (i == 0) ptr[n] = total;
}

// No atomics: slot = ptr[d] + rank[i]. Edge record packs (src, ew).
__global__ void fill_edges(const int* __restrict__ ei, const float* __restrict__ ew,
                           const int* __restrict__ ptr, const int* __restrict__ rank,
                           uint2* __restrict__ edges, int e) {
    int i = blockIdx.x * 256 + threadIdx.x;
    if (i < e) {
        int r = ei[i];           // source
        int d = ei[e + i];       // dest
        int p = ptr[d] + rank[i];
        edges[p] = make_uint2((unsigned)r, __float_as_uint(ew[i]));
    }
}

// ------------------------------------------------------------------
// MFMA bf16 GEMM: block = 256 thr (4 waves), tile 64(M) x (32*NT)(N),
// K-step 32, wave = 32x(16*NT): 2x NT mfma_f32_16x16x32_bf16.
// EPI 0: C0 bf16 [M][128] = rowscale[m] * val   (conv tmp, dinv folded)
// EPI 1: n<128 -> relu+bias -> C0 bf16; n<168 -> C1 fp32 [M][40];
//        n<170 -> C2 fp32 [M][2]   (bias from bcat)
// ------------------------------------------------------------------
template <int EPI, int NT, int AF32>
__global__ __launch_bounds__(256) void gemm_mfma(
    const void* __restrict__ Avoid, const unsigned short* __restrict__ BT,
    int M, int K,
    unsigned short* __restrict__ C0, float* __restrict__ C1, float* __restrict__ C2,
    const float* __restrict__ bias, const float* __restrict__ rowscale) {
    constexpr int NB = 32 * NT;                  // full N width
    __shared__ __align__(16) unsigned short Ast[64 * 40];
    __shared__ __align__(16) unsigned short Bst[NB * 40];

    int tid = threadIdx.x;
    int m0 = blockIdx.x * 64;
    int wave = tid >> 6, lane = tid & 63;
    int quad = lane >> 4, mi = lane & 15;
    int wm = (wave >> 1) * 32;                   // wave M offset (0 or 32)
    int wn = (wave & 1) * (16 * NT);             // wave N offset

    int srow = tid >> 2;                         // 0..63
    int sk8 = (tid & 3) * 8;                     // 0,8,16,24

    int arow = m0 + srow; if (arow >= M) arow = M - 1;

    floatx4 acc[2][NT] = {};

    for (int kc = 0; kc < K; kc += 32) {
        if (AF32) {
            const float* Af = (const float*)Avoid;
            const float4* ap = (const float4*)(Af + (size_t)arow * K + kc + sk8);
            float4 f0 = ap[0], f1 = ap[1];
            union { unsigned short us[8]; uint4 v; } pk;
            pk.us[0] = f2bf(f0.x); pk.us[1] = f2bf(f0.y);
            pk.us[2] = f2bf(f0.z); pk.us[3] = f2bf(f0.w);
            pk.us[4] = f2bf(f1.x); pk.us[5] = f2bf(f1.y);
            pk.us[6] = f2bf(f1.z); pk.us[7] = f2bf(f1.w);
            *(uint4*)&Ast[srow * 40 + sk8] = pk.v;
        } else {
            const unsigned short* Ab = (const unsigned short*)Avoid;
            uint4 av = *(const uint4*)(Ab + (size_t)arow * K + kc + sk8);
            *(uint4*)&Ast[srow * 40 + sk8] = av;
        }
#pragma unroll
        for (int i = tid; i < NB * 4; i += 256) {
            int brow = i >> 2;
            int bk8 = (i & 3) * 8;
            uint4 bv = *(const uint4*)(BT + (size_t)brow * K + kc + bk8);
            *(uint4*)&Bst[brow * 40 + bk8] = bv;
        }
        __syncthreads();

        short8 a0 = *(const short8*)&Ast[(wm + mi) * 40 + quad * 8];
        short8 a1 = *(const short8*)&Ast[(wm + 16 + mi) * 40 + quad * 8];
#pragma unroll
        for (int nt = 0; nt < NT; ++nt) {
            short8 b = *(const short8*)&Bst[(wn + nt * 16 + mi) * 40 + quad * 8];
            acc[0][nt] = __builtin_amdgcn_mfma_f32_16x16x32_bf16(a0, b, acc[0][nt], 0, 0, 0);
            acc[1][nt] = __builtin_amdgcn_mfma_f32_16x16x32_bf16(a1, b, acc[1][nt], 0, 0, 0);
        }
        __syncthreads();
    }

    // ---- epilogue: D layout col=lane&15, row=quad*4+r ----
#pragma unroll
    for (int mt = 0; mt < 2; ++mt) {
#pragma unroll
        for (int nt = 0; nt < NT; ++nt) {
            floatx4 v = acc[mt][nt];
            int gn = wn + nt * 16 + mi;
#pragma unroll
            for (int r = 0; r < 4; ++r) {
                int gm = m0 + wm + mt * 16 + quad * 4 + r;
                if (gm >= M) continue;
                float val = v[r];
                if (EPI == 0) {
                    C0[(size_t)gm * 128 + gn] = f2bf(rowscale[gm] * val);
                } else {
                    val += bias[gn];
                    if (gn < 128)      C0[(size_t)gm * 128 + gn] = f2bf(fmaxf(val, 0.f));
                    else if (gn < 168) C1[(size_t)gm * 40 + (gn - 128)] = val;
                    else if (gn < 170) C2[(size_t)gm * 2 + (gn - 168)] = val;
                }
            }
        }
    }
}

// ------------------------------------------------------------------
// GCN propagation, dst-CSR, bf16 messages, dinv pre-folded into rows:
// out[d] = relu(dinv[d] * (tmp'[d] + sum_p ew_p * tmp'[src_p]) + bias)
// One WAVE per dst node: 64 lanes x bf16x2 = full 128-feature row.
// ------------------------------------------------------------------
__global__ __launch_bounds__(256) void propagate(
    const unsigned int* __restrict__ tmp2,    // [M][64] packed bf16x2 (dinv-scaled)
    unsigned int* __restrict__ out2,          // [M][64] packed bf16x2
    const float* __restrict__ bias, const float* __restrict__ dinv,
    const int* __restrict__ ptr, const uint2* __restrict__ edges, int n) {
    int wave = threadIdx.x >> 6, lane = threadIdx.x & 63;
    int d = blockIdx.x * 4 + wave;
    if (d >= n) return;

    unsigned u = tmp2[(size_t)d * 64 + lane];   // self loop (tmp'[d])
    float acc0 = bflo(u);
    float acc1 = bfhi(u);

    int p = ptr[d], p1 = ptr[d + 1];
    for (; p + 4 <= p1; p += 4) {
        uint2 q0 = edges[p], q1 = edges[p + 1], q2 = edges[p + 2], q3 = edges[p + 3];
        unsigned a = tmp2[(size_t)q0.x * 64 + lane];
        unsigned b = tmp2[(size_t)q1.x * 64 + lane];
        unsigned c = tmp2[(size_t)q2.x * 64 + lane];
        unsigned e = tmp2[(size_t)q3.x * 64 + lane];
        float w0 = __uint_as_float(q0.y), w1 = __uint_as_float(q1.y);
        float w2 = __uint_as_float(q2.y), w3 = __uint_as_float(q3.y);
        acc0 += w0 * bflo(a); acc1 += w0 * bfhi(a);
        acc0 += w1 * bflo(b); acc1 += w1 * bfhi(b);
        acc0 += w2 * bflo(c); acc1 += w2 * bfhi(c);
        acc0 += w3 * bflo(e); acc1 += w3 * bfhi(e);
    }
    for (; p < p1; ++p) {
        uint2 q = edges[p];
        unsigned a = tmp2[(size_t)q.x * 64 + lane];
        float w = __uint_as_float(q.y);
        acc0 += w * bflo(a); acc1 += w * bfhi(a);
    }
    float di = dinv[d];
    float v0 = fmaxf(di * acc0 + bias[2 * lane], 0.f);
    float v1 = fmaxf(di * acc1 + bias[2 * lane + 1], 0.f);
    out2[(size_t)d * 64 + lane] = (unsigned)f2bf(v0) | ((unsigned)f2bf(v1) << 16);
}

// ------------------------------------------------------------------
// Final: out = (h2 @ W2 + b2) * a0 + wide * a1, attn = softmax(logits)
// ------------------------------------------------------------------
__global__ void final_k(const unsigned short* __restrict__ h2, const float* __restrict__ wide,
                        const float* __restrict__ attnL, const float* __restrict__ W2,
                        const float* __restrict__ b2, float* __restrict__ out) {
    __shared__ __align__(16) float hs[8][132];
    __shared__ __align__(16) float w2t[40][132];
    int tid = threadIdx.x;
    int m0 = blockIdx.x * 8;

    for (int idx = tid; idx < 8 * 128; idx += 320) {
        hs[idx >> 7][idx & 127] = bf2f(h2[(size_t)m0 * 128 + idx]);
    }
    for (int idx = tid; idx < 40 * 128; idx += 320) {
        int c = idx >> 7, k = idx & 127;
        w2t[c][k] = W2[k * 40 + c];
    }
    __syncthreads();

    int c = tid % 40;
    int nl = tid / 40;   // 0..7
    float acc = 0.f;
#pragma unroll
    for (int k = 0; k < 128; k += 4) {
        float4 h4 = *(const float4*)&hs[nl][k];
        float4 w4 = *(const float4*)&w2t[c][k];
        acc += h4.x * w4.x + h4.y * w4.y + h4.z * w4.z + h4.w * w4.w;
    }
    int m = m0 + nl;
    float l0 = attnL[m * 2], l1 = attnL[m * 2 + 1];
    float mx = fmaxf(l0, l1);
    float e0 = __expf(l0 - mx), e1 = __expf(l1 - mx);
    float inv = 1.f / (e0 + e1);
    out[(size_t)m * 40 + c] = (acc + b2[c]) * (e0 * inv) + wide[(size_t)m * 40 + c] * (e1 * inv);
}

// ------------------------------------------------------------------
extern "C" void kernel_launch(void* const* d_in, const int* in_sizes, int n_in,
                              void* d_out, int out_size, void* d_ws, size_t ws_size,
                              hipStream_t stream) {
    (void)in_sizes; (void)n_in; (void)out_size; (void)ws_size;
    const float* x   = (const float*)d_in[0];
    const int*   ei  = (const int*)d_in[1];
    const float* ew  = (const float*)d_in[2];
    const float* W1  = (const float*)d_in[3];
    const float* b1  = (const float*)d_in[4];
    const float* Wc1 = (const float*)d_in[5];
    const float* bc1 = (const float*)d_in[6];
    const float* Wc2 = (const float*)d_in[7];
    const float* bc2 = (const float*)d_in[8];
    const float* W2  = (const float*)d_in[9];
    const float* b2  = (const float*)d_in[10];
    const float* Ww  = (const float*)d_in[11];
    const float* bw  = (const float*)d_in[12];
    const float* Wa  = (const float*)d_in[13];
    const float* ba  = (const float*)d_in[14];
    float* out = (float*)d_out;

    const int N = N_NODES, E = N_EDGES;
    char* ws = (char*)d_ws;
    size_t off = 0;
    auto alloc = [&](size_t bytes) -> void* {
        void* p = ws + off;
        off = (off + bytes + 255) & ~(size_t)255;
        return p;
    };
    unsigned short* bufA = (unsigned short*)alloc((size_t)N * 128 * 2);  // h ping (bf16)
    unsigned short* bufB = (unsigned short*)alloc((size_t)N * 128 * 2);  // h pong (bf16)
    float* wide  = (float*)alloc((size_t)N * 40 * 4);
    float* attnL = (float*)alloc((size_t)N * 2 * 4);
    float* dinv  = (float*)alloc((size_t)N * 4);
    unsigned long long* packed = (unsigned long long*)alloc((size_t)N * 8);
    int*   ptr   = (int*)alloc((size_t)(N + 1) * 4);
    int*   rank  = (int*)alloc((size_t)E * 4);
    int*   bsum  = (int*)alloc(1024 * 4);
    uint2* edges = (uint2*)alloc((size_t)E * 8);
    unsigned short* WcatT = (unsigned short*)alloc((size_t)192 * 512 * 2);
    unsigned short* Wc1T  = (unsigned short*)alloc((size_t)128 * 128 * 2);
    unsigned short* Wc2T  = (unsigned short*)alloc((size_t)128 * 128 * 2);
    float* bcat  = (float*)alloc(192 * 4);

    // --- weight packing (bf16, transposed to [n][K]) ---
    pack_wcatT<<<192, 256, 0, stream>>>(W1, b1, Ww, bw, Wa, ba, WcatT, bcat);
    pack_wcT<<<256, 128, 0, stream>>>(Wc1, Wc2, Wc1T, Wc2T);

    // --- graph preprocessing: 1 packed atomic per edge ---
    init_packed<<<(N + 255) / 256, 256, 0, stream>>>(packed, N);
    deg_rank<<<(E + 255) / 256, 256, 0, stream>>>(ei, ew, packed, rank, E);
    finalize_dinv<<<(N + 255) / 256, 256, 0, stream>>>(packed, dinv, N);
    int nb = (N + 1023) / 1024;
    scan_blocks<<<nb, 1024, 0, stream>>>(packed, ptr, bsum, N);
    scan_bsums<<<1, 1024, 0, stream>>>(bsum, nb);
    scan_add<<<nb, 1024, 0, stream>>>(ptr, bsum, N, E);
    fill_edges<<<(E + 255) / 256, 256, 0, stream>>>(ei, ew, ptr, rank, edges, E);

    const int MB = (N + 63) / 64;   // 1563 m-blocks

    // --- fused input GEMM (fp32 A, bf16 MFMA): h0/wide/attnL ---
    gemm_mfma<1, 6, 1><<<MB, 256, 0, stream>>>(x, WcatT, N, 512, bufA, wide, attnL, bcat, nullptr);

    // --- conv layer 1 (tmp rows scaled by dinv in epilogue) ---
    gemm_mfma<0, 4, 0><<<MB, 256, 0, stream>>>(bufA, Wc1T, N, 128, bufB, nullptr, nullptr, nullptr, dinv);
    propagate<<<(N + 3) / 4, 256, 0, stream>>>((const unsigned int*)bufB, (unsigned int*)bufA,
                                               bc1, dinv, ptr, edges, N);

    // --- conv layer 2 ---
    gemm_mfma<0, 4, 0><<<MB, 256, 0, stream>>>(bufA, Wc2T, N, 128, bufB, nullptr, nullptr, nullptr, dinv);
    propagate<<<(N + 3) / 4, 256, 0, stream>>>((const unsigned int*)bufB, (unsigned int*)bufA,
                                               bc2, dinv, ptr, edges, N);

    // --- final fusion ---
    final_k<<<N / 8, 320, 0, stream>>>(bufA, wide, attnL, W2, b2, out);
}

// Round 4
// 912.376 us; speedup vs baseline: 2.0869x; 1.0891x over previous
//
#include <hip/hip_runtime.h>
#include <hip/hip_bf16.h>
#include <cstdint>

#define N_NODES 100000
#define N_EDGES 3200000

typedef __attribute__((ext_vector_type(8))) short short8;
typedef __attribute__((ext_vector_type(4))) float floatx4;

#define FXS 8388608.0f           // 2^23 fixed-point scale for degree accum
#define MASK40 0xFFFFFFFFFFull

__device__ __forceinline__ unsigned short f2bf(float f) {
    unsigned u = __float_as_uint(f);
    u += 0x7fff + ((u >> 16) & 1);          // round-to-nearest-even
    return (unsigned short)(u >> 16);
}
__device__ __forceinline__ float bf2f(unsigned short s) {
    return __uint_as_float(((unsigned)s) << 16);
}
__device__ __forceinline__ float bflo(unsigned u) {
    return __uint_as_float(u << 16);
}
__device__ __forceinline__ float bfhi(unsigned u) {
    return __uint_as_float(u & 0xffff0000u);
}
__device__ __forceinline__ unsigned pack_bf2(float a, float b) {
    union { __hip_bfloat162 h2; unsigned u; } cv;
    cv.h2 = __float22bfloat162_rn(make_float2(a, b));   // v_cvt_pk_bf16_f32
    return cv.u;
}

// ------------------------------------------------------------------
// Setup: pack WcatT[192][512] / Wc1T / Wc2T (bf16, transposed) + zero packed[]
// ------------------------------------------------------------------
__global__ void setup_misc(const float* __restrict__ W1, const float* __restrict__ b1,
                           const float* __restrict__ Ww, const float* __restrict__ bw,
                           const float* __restrict__ Wa, const float* __restrict__ ba,
                           const float* __restrict__ Wc1, const float* __restrict__ Wc2,
                           unsigned short* __restrict__ WcatT, float* __restrict__ bcat,
                           unsigned short* __restrict__ Wc1T, unsigned short* __restrict__ Wc2T,
                           unsigned long long* __restrict__ packed, int n) {
    int bid = blockIdx.x, tid = threadIdx.x;
    if (bid < 192) {
        int c = bid;
        for (int kk = tid; kk < 512; kk += 256) {
            float v;
            if (c < 128)      v = W1[kk * 128 + c];
            else if (c < 168) v = Ww[kk * 40 + (c - 128)];
            else if (c < 170) v = Wa[kk * 2 + (c - 168)];
            else              v = 0.f;
            WcatT[(size_t)c * 512 + kk] = f2bf(v);
        }
        if (tid == 0) {
            float b;
            if (c < 128)      b = b1[c];
            else if (c < 168) b = bw[c - 128];
            else if (c < 170) b = ba[c - 168];
            else              b = 0.f;
            bcat[c] = b;
        }
    } else if (bid < 320) {
        int c = bid - 192;
        if (tid < 128) Wc1T[(size_t)c * 128 + tid] = f2bf(Wc1[tid * 128 + c]);
        else { int k = tid - 128; Wc2T[(size_t)c * 128 + k] = f2bf(Wc2[k * 128 + c]); }
    } else {
        int i = (bid - 320) * 256 + tid;
        if (i < n) packed[i] = 0ull;
    }
}

// ------------------------------------------------------------------
// MFMA bf16 GEMM body: tile 64(M) x (32*NT)(N), K-step 32, 4 waves.
// EPI 0: C0 bf16 [M][128] = rowscale[m] * val
// EPI 1: n<128 -> relu+bias -> C0 bf16; n<168 -> C1 fp32; n<170 -> C2 fp32
// ------------------------------------------------------------------
template <int EPI, int NT, int AF32>
__device__ __forceinline__ void gemm_body(
    int mblk, const void* __restrict__ Avoid, const unsigned short* __restrict__ BT,
    int M, int K,
    unsigned short* __restrict__ C0, float* __restrict__ C1, float* __restrict__ C2,
    const float* __restrict__ bias, const float* __restrict__ rowscale) {
    constexpr int NB = 32 * NT;
    __shared__ __align__(16) unsigned short Ast[64 * 40];
    __shared__ __align__(16) unsigned short Bst[NB * 40];

    int tid = threadIdx.x;
    int m0 = mblk * 64;
    int wave = tid >> 6, lane = tid & 63;
    int quad = lane >> 4, mi = lane & 15;
    int wm = (wave >> 1) * 32;
    int wn = (wave & 1) * (16 * NT);

    int srow = tid >> 2;
    int sk8 = (tid & 3) * 8;

    int arow = m0 + srow; if (arow >= M) arow = M - 1;

    floatx4 acc[2][NT] = {};

    for (int kc = 0; kc < K; kc += 32) {
        if (AF32) {
            const float* Af = (const float*)Avoid;
            const float4* ap = (const float4*)(Af + (size_t)arow * K + kc + sk8);
            float4 f0 = ap[0], f1 = ap[1];
            uint4 pk;
            pk.x = pack_bf2(f0.x, f0.y);
            pk.y = pack_bf2(f0.z, f0.w);
            pk.z = pack_bf2(f1.x, f1.y);
            pk.w = pack_bf2(f1.z, f1.w);
            *(uint4*)&Ast[srow * 40 + sk8] = pk;
        } else {
            const unsigned short* Ab = (const unsigned short*)Avoid;
            uint4 av = *(const uint4*)(Ab + (size_t)arow * K + kc + sk8);
            *(uint4*)&Ast[srow * 40 + sk8] = av;
        }
#pragma unroll
        for (int i = tid; i < NB * 4; i += 256) {
            int brow = i >> 2;
            int bk8 = (i & 3) * 8;
            uint4 bv = *(const uint4*)(BT + (size_t)brow * K + kc + bk8);
            *(uint4*)&Bst[brow * 40 + bk8] = bv;
        }
        __syncthreads();

        short8 a0 = *(const short8*)&Ast[(wm + mi) * 40 + quad * 8];
        short8 a1 = *(const short8*)&Ast[(wm + 16 + mi) * 40 + quad * 8];
#pragma unroll
        for (int nt = 0; nt < NT; ++nt) {
            short8 b = *(const short8*)&Bst[(wn + nt * 16 + mi) * 40 + quad * 8];
            acc[0][nt] = __builtin_amdgcn_mfma_f32_16x16x32_bf16(a0, b, acc[0][nt], 0, 0, 0);
            acc[1][nt] = __builtin_amdgcn_mfma_f32_16x16x32_bf16(a1, b, acc[1][nt], 0, 0, 0);
        }
        __syncthreads();
    }

#pragma unroll
    for (int mt = 0; mt < 2; ++mt) {
#pragma unroll
        for (int nt = 0; nt < NT; ++nt) {
            floatx4 v = acc[mt][nt];
            int gn = wn + nt * 16 + mi;
#pragma unroll
            for (int r = 0; r < 4; ++r) {
                int gm = m0 + wm + mt * 16 + quad * 4 + r;
                if (gm >= M) continue;
                float val = v[r];
                if (EPI == 0) {
                    C0[(size_t)gm * 128 + gn] = f2bf(rowscale[gm] * val);
                } else {
                    val += bias[gn];
                    if (gn < 128)      C0[(size_t)gm * 128 + gn] = f2bf(fmaxf(val, 0.f));
                    else if (gn < 168) C1[(size_t)gm * 40 + (gn - 128)] = val;
                    else if (gn < 170) C2[(size_t)gm * 2 + (gn - 168)] = val;
                }
            }
        }
    }
}

// ------------------------------------------------------------------
// mega1: blocks with bid%9==0 run the input GEMM; the rest run deg_rank
// (1 packed 64-bit atomic per edge; return value = rank within dst).
// ------------------------------------------------------------------
__global__ __launch_bounds__(256) void mega1(
    const float* __restrict__ x, const unsigned short* __restrict__ WcatT,
    unsigned short* __restrict__ h0, float* __restrict__ wide, float* __restrict__ attnL,
    const float* __restrict__ bcat,
    const int* __restrict__ ei, const float* __restrict__ ew,
    unsigned long long* __restrict__ packed, int* __restrict__ rank, int M, int e) {
    int bid = blockIdx.x;
    int q = bid / 9;
    if (bid - q * 9 == 0) {
        gemm_body<1, 6, 1>(q, x, WcatT, M, 512, h0, wide, attnL, bcat, nullptr);
    } else {
        int i = (bid - q - 1) * 256 + threadIdx.x;
        if (i < e) {
            int d = ei[e + i];               // dst = edge_index[1]
            unsigned fx = (unsigned)(ew[i] * FXS);
            unsigned long long old =
                atomicAdd(&packed[d], (1ull << 40) | (unsigned long long)fx);
            rank[i] = (int)(old >> 40);
        }
    }
}

// ------------------------------------------------------------------
// mega2: bid%9==0 -> conv1 GEMM (rowscale=dinv); rest -> fill edges
// (no atomics: slot = ptr[d] + rank[i], record packs (src, ew)).
// ------------------------------------------------------------------
__global__ __launch_bounds__(256) void mega2(
    const unsigned short* __restrict__ h0, const unsigned short* __restrict__ Wc1T,
    unsigned short* __restrict__ tmpB, const float* __restrict__ dinv,
    const int* __restrict__ ei, const float* __restrict__ ew,
    const int* __restrict__ ptr, const int* __restrict__ rank,
    uint2* __restrict__ edges, int M, int e) {
    int bid = blockIdx.x;
    int q = bid / 9;
    if (bid - q * 9 == 0) {
        gemm_body<0, 4, 0>(q, h0, Wc1T, M, 128, tmpB, nullptr, nullptr, nullptr, dinv);
    } else {
        int i = (bid - q - 1) * 256 + threadIdx.x;
        if (i < e) {
            int r = ei[i];
            int d = ei[e + i];
            edges[ptr[d] + rank[i]] = make_uint2((unsigned)r, __float_as_uint(ew[i]));
        }
    }
}

__global__ __launch_bounds__(256) void gemm_conv(
    const unsigned short* __restrict__ A, const unsigned short* __restrict__ BT,
    unsigned short* __restrict__ C0, const float* __restrict__ rowscale, int M) {
    gemm_body<0, 4, 0>(blockIdx.x, A, BT, M, 128, C0, nullptr, nullptr, nullptr, rowscale);
}

// ------------------------------------------------------------------
// Scan over degree counts + dinv computation fused.
// ------------------------------------------------------------------
__global__ void scan_blocks(const unsigned long long* __restrict__ packed,
                            int* __restrict__ ptr, int* __restrict__ bsum,
                            float* __restrict__ dinv, int n) {
    __shared__ int s[1024];
    int tid = threadIdx.x;
    int i = blockIdx.x * 1024 + tid;
    int v = 0;
    if (i < n) {
        unsigned long long pk = packed[i];
        v = (int)(pk >> 40);
        float deg = 1.0f + (float)(pk & MASK40) * (1.0f / FXS);  // + self-loop
        dinv[i] = rsqrtf(deg);
    }
    s[tid] = v;
    __syncthreads();
    for (int off = 1; off < 1024; off <<= 1) {
        int t = (tid >= off) ? s[tid - off] : 0;
        __syncthreads();
        s[tid] += t;
        __syncthreads();
    }
    if (i < n) ptr[i] = s[tid] - v;              // exclusive
    if (tid == 1023) bsum[blockIdx.x] = s[1023];
}

__global__ void scan_bsums(int* bsum, int nb) {
    __shared__ int s[1024];
    int tid = threadIdx.x;
    int v = (tid < nb) ? bsum[tid] : 0;
    s[tid] = v;
    __syncthreads();
    for (int off = 1; off < 1024; off <<= 1) {
        int t = (tid >= off) ? s[tid - off] : 0;
        __syncthreads();
        s[tid] += t;
        __syncthreads();
    }
    if (tid < nb) bsum[tid] = s[tid] - v;        // exclusive
}

__global__ void scan_add(int* __restrict__ ptr, const int* __restrict__ bsum,
                         int n, int total) {
    int i = blockIdx.x * 1024 + threadIdx.x;
    if (i < n) ptr[i] += bsum[blockIdx.x];
    if (i == 0) ptr[n] = total;
}

// ------------------------------------------------------------------
// GCN propagation, dst-CSR, bf16 messages, dinv pre-folded into rows:
// out[d] = relu(dinv[d] * (tmp'[d] + sum ew*tmp'[src]) + bias)
// One WAVE per dst node, 8-deep edge unroll for MLP.
// ------------------------------------------------------------------
__global__ __launch_bounds__(256) void propagate(
    const unsigned int* __restrict__ tmp2,    // [M][64] packed bf16x2 (dinv-scaled)
    unsigned int* __restrict__ out2,
    const float* __restrict__ bias, const float* __restrict__ dinv,
    const int* __restrict__ ptr, const uint2* __restrict__ edges, int n) {
    int wave = threadIdx.x >> 6, lane = threadIdx.x & 63;
    int d = blockIdx.x * 4 + wave;
    if (d >= n) return;

    unsigned u = tmp2[(size_t)d * 64 + lane];   // self loop
    float acc0 = bflo(u);
    float acc1 = bfhi(u);

    int p = ptr[d], p1 = ptr[d + 1];
    for (; p + 8 <= p1; p += 8) {
        uint2 q[8];
#pragma unroll
        for (int j = 0; j < 8; ++j) q[j] = edges[p + j];
        unsigned rv[8];
#pragma unroll
        for (int j = 0; j < 8; ++j) rv[j] = tmp2[(size_t)q[j].x * 64 + lane];
#pragma unroll
        for (int j = 0; j < 8; ++j) {
            float w = __uint_as_float(q[j].y);
            acc0 += w * bflo(rv[j]); acc1 += w * bfhi(rv[j]);
        }
    }
    for (; p < p1; ++p) {
        uint2 q = edges[p];
        unsigned a = tmp2[(size_t)q.x * 64 + lane];
        float w = __uint_as_float(q.y);
        acc0 += w * bflo(a); acc1 += w * bfhi(a);
    }
    float di = dinv[d];
    float v0 = fmaxf(di * acc0 + bias[2 * lane], 0.f);
    float v1 = fmaxf(di * acc1 + bias[2 * lane + 1], 0.f);
    out2[(size_t)d * 64 + lane] = (unsigned)f2bf(v0) | ((unsigned)f2bf(v1) << 16);
}

// ------------------------------------------------------------------
// Final: out = (h2 @ W2 + b2) * a0 + wide * a1, attn = softmax(logits)
// ------------------------------------------------------------------
__global__ void final_k(const unsigned short* __restrict__ h2, const float* __restrict__ wide,
                        const float* __restrict__ attnL, const float* __restrict__ W2,
                        const float* __restrict__ b2, float* __restrict__ out) {
    __shared__ __align__(16) float hs[8][132];
    __shared__ __align__(16) float w2t[40][132];
    int tid = threadIdx.x;
    int m0 = blockIdx.x * 8;

    for (int idx = tid; idx < 8 * 128; idx += 320) {
        hs[idx >> 7][idx & 127] = bf2f(h2[(size_t)m0 * 128 + idx]);
    }
    for (int idx = tid; idx < 40 * 128; idx += 320) {
        int c = idx >> 7, k = idx & 127;
        w2t[c][k] = W2[k * 40 + c];
    }
    __syncthreads();

    int c = tid % 40;
    int nl = tid / 40;
    float acc = 0.f;
#pragma unroll
    for (int k = 0; k < 128; k += 4) {
        float4 h4 = *(const float4*)&hs[nl][k];
        float4 w4 = *(const float4*)&w2t[c][k];
        acc += h4.x * w4.x + h4.y * w4.y + h4.z * w4.z + h4.w * w4.w;
    }
    int m = m0 + nl;
    float l0 = attnL[m * 2], l1 = attnL[m * 2 + 1];
    float mx = fmaxf(l0, l1);
    float e0 = __expf(l0 - mx), e1 = __expf(l1 - mx);
    float inv = 1.f / (e0 + e1);
    out[(size_t)m * 40 + c] = (acc + b2[c]) * (e0 * inv) + wide[(size_t)m * 40 + c] * (e1 * inv);
}

// ------------------------------------------------------------------
extern "C" void kernel_launch(void* const* d_in, const int* in_sizes, int n_in,
                              void* d_out, int out_size, void* d_ws, size_t ws_size,
                              hipStream_t stream) {
    (void)in_sizes; (void)n_in; (void)out_size; (void)ws_size;
    const float* x   = (const float*)d_in[0];
    const int*   ei  = (const int*)d_in[1];
    const float* ew  = (const float*)d_in[2];
    const float* W1  = (const float*)d_in[3];
    const float* b1  = (const float*)d_in[4];
    const float* Wc1 = (const float*)d_in[5];
    const float* bc1 = (const float*)d_in[6];
    const float* Wc2 = (const float*)d_in[7];
    const float* bc2 = (const float*)d_in[8];
    const float* W2  = (const float*)d_in[9];
    const float* b2  = (const float*)d_in[10];
    const float* Ww  = (const float*)d_in[11];
    const float* bw  = (const float*)d_in[12];
    const float* Wa  = (const float*)d_in[13];
    const float* ba  = (const float*)d_in[14];
    float* out = (float*)d_out;

    const int N = N_NODES, E = N_EDGES;
    char* ws = (char*)d_ws;
    size_t off = 0;
    auto alloc = [&](size_t bytes) -> void* {
        void* p = ws + off;
        off = (off + bytes + 255) & ~(size_t)255;
        return p;
    };
    unsigned short* bufA = (unsigned short*)alloc((size_t)N * 128 * 2);
    unsigned short* bufB = (unsigned short*)alloc((size_t)N * 128 * 2);
    float* wide  = (float*)alloc((size_t)N * 40 * 4);
    float* attnL = (float*)alloc((size_t)N * 2 * 4);
    float* dinv  = (float*)alloc((size_t)N * 4);
    unsigned long long* packed = (unsigned long long*)alloc((size_t)N * 8);
    int*   ptr   = (int*)alloc((size_t)(N + 1) * 4);
    int*   rank  = (int*)alloc((size_t)E * 4);
    int*   bsum  = (int*)alloc(1024 * 4);
    uint2* edges = (uint2*)alloc((size_t)E * 8);
    unsigned short* WcatT = (unsigned short*)alloc((size_t)192 * 512 * 2);
    unsigned short* Wc1T  = (unsigned short*)alloc((size_t)128 * 128 * 2);
    unsigned short* Wc2T  = (unsigned short*)alloc((size_t)128 * 128 * 2);
    float* bcat  = (float*)alloc(192 * 4);

    const int MB = (N + 63) / 64;          // 1563 gemm m-blocks
    const int EB = (E + 255) / 256;        // 12500 edge blocks
    const int MEGA = MB * 9;               // 14067 >= MB + EB interleaved 1:8

    // setup: weight packs + packed[] zero-init
    setup_misc<<<320 + (N + 255) / 256, 256, 0, stream>>>(
        W1, b1, Ww, bw, Wa, ba, Wc1, Wc2, WcatT, bcat, Wc1T, Wc2T, packed, N);

    // mega1: input GEMM (x -> h0/wide/attnL) overlapped with deg_rank atomics
    mega1<<<MEGA, 256, 0, stream>>>(x, WcatT, bufA, wide, attnL, bcat,
                                    ei, ew, packed, rank, N, E);

    // scans (+ dinv)
    int nb = (N + 1023) / 1024;
    scan_blocks<<<nb, 1024, 0, stream>>>(packed, ptr, bsum, dinv, N);
    scan_bsums<<<1, 1024, 0, stream>>>(bsum, nb);
    scan_add<<<nb, 1024, 0, stream>>>(ptr, bsum, N, E);

    // mega2: conv1 GEMM (h0 -> tmpB, dinv-scaled) overlapped with edge fill
    mega2<<<MEGA, 256, 0, stream>>>(bufA, Wc1T, bufB, dinv, ei, ew, ptr, rank, edges, N, E);
    propagate<<<(N + 3) / 4, 256, 0, stream>>>((const unsigned int*)bufB, (unsigned int*)bufA,
                                               bc1, dinv, ptr, edges, N);

    // conv layer 2
    gemm_conv<<<MB, 256, 0, stream>>>(bufA, Wc2T, bufB, dinv, N);
    propagate<<<(N + 3) / 4, 256, 0, stream>>>((const unsigned int*)bufB, (unsigned int*)bufA,
                                               bc2, dinv, ptr, edges, N);

    // final fusion
    final_k<<<N / 8, 320, 0, stream>>>(bufA, wide, attnL, W2, b2, out);
}